// Round 4
// baseline (450.340 us; speedup 1.0000x reference)
//
#include <hip/hip_runtime.h>
#include <hip/hip_fp16.h>

typedef _Float16 f16;
typedef _Float16 f16x8 __attribute__((ext_vector_type(8)));
typedef float f32x4 __attribute__((ext_vector_type(4)));

__device__ __forceinline__ float h2f(__half v) { return __half2float(v); }
__device__ __forceinline__ __half f2h(float v) { return __float2half(v); }

#define SCAN_CHUNK 2048
#define ASTRIDE 136  // 128 + 8 pad; 272B row stride, 16B-aligned

// bucketed edge sort parameters
#define BSHIFT 10
#define BROWS (1 << BSHIFT)   // rows per bucket
#define MAXB 1024             // max buckets supported by fast path
#define TILE 4096             // edges per binning block

// ---------------------------------------------------------------- sentinel: zero output (ws too small)
__global__ void zero_out_kernel(float* __restrict__ out, int total) {
    int i = blockIdx.x * blockDim.x + threadIdx.x;
    if (i < total) out[i] = 0.0f;
}

// ---------------------------------------------------------------- init: ego0(fp16) = concat(user,item)
__global__ void init_kernel(const float* __restrict__ user, const float* __restrict__ item,
                            __half* __restrict__ ego0, int usz, int total) {
    int i = blockIdx.x * blockDim.x + threadIdx.x;
    if (i >= total) return;
    float f = (i < usz) ? user[i] : item[i - usz];
    ego0[i] = f2h(f);
}

// ---------------------------------------------------------------- FALLBACK-ONLY CSR build (global atomics)
__global__ void hist_kernel(const int* __restrict__ rows, int* __restrict__ cnt, int nnz) {
    int i = blockIdx.x * blockDim.x + threadIdx.x;
    if (i < nnz) atomicAdd(&cnt[rows[i]], 1);
}

__global__ void scan_pass1(const int* __restrict__ cnt, int* __restrict__ bsum, int n) {
    __shared__ int wt[4];
    int tid = threadIdx.x;
    int base = blockIdx.x * SCAN_CHUNK + tid * 8;
    int s = 0;
    #pragma unroll
    for (int k = 0; k < 8; ++k) { int i = base + k; if (i < n) s += cnt[i]; }
    #pragma unroll
    for (int o = 32; o > 0; o >>= 1) s += __shfl_down(s, o, 64);
    int lane = tid & 63, wid = tid >> 6;
    if (lane == 0) wt[wid] = s;
    __syncthreads();
    if (tid == 0) bsum[blockIdx.x] = wt[0] + wt[1] + wt[2] + wt[3];
}

__global__ void scan_pass2(int* __restrict__ bsum, int nb, int* __restrict__ total) {
    if (threadIdx.x == 0) {
        int run = 0;
        for (int b = 0; b < nb; ++b) { int v = bsum[b]; bsum[b] = run; run += v; }
        *total = run;
    }
}

__global__ void scan_pass3(int* __restrict__ cnt, const int* __restrict__ bsum,
                           int* __restrict__ rptr, int n, const int* __restrict__ total) {
    __shared__ int wt[4];
    int tid = threadIdx.x;
    int base = blockIdx.x * SCAN_CHUNK + tid * 8;
    int v[8];
    int s = 0;
    #pragma unroll
    for (int k = 0; k < 8; ++k) { int i = base + k; v[k] = (i < n) ? cnt[i] : 0; s += v[k]; }
    int lane = tid & 63, wid = tid >> 6;
    int xs = s;
    #pragma unroll
    for (int o = 1; o < 64; o <<= 1) { int t = __shfl_up(xs, o, 64); if (lane >= o) xs += t; }
    if (lane == 63) wt[wid] = xs;
    __syncthreads();
    int wexcl = 0;
    for (int w = 0; w < wid; ++w) wexcl += wt[w];
    int run = bsum[blockIdx.x] + wexcl + (xs - s);
    #pragma unroll
    for (int k = 0; k < 8; ++k) {
        int i = base + k;
        if (i < n) { rptr[i] = run; cnt[i] = run; }  // cnt becomes scatter cursor
        run += v[k];
    }
    if (blockIdx.x == 0 && tid == 0) rptr[n] = *total;
}

__global__ void scatter_kernel(const int* __restrict__ rows, const int* __restrict__ cols,
                               const float* __restrict__ vals, int* __restrict__ cursor,
                               int2* __restrict__ edges, int nnz) {
    int i = blockIdx.x * blockDim.x + threadIdx.x;
    if (i >= nnz) return;
    int r = rows[i];
    int pos = atomicAdd(&cursor[r], 1);
    edges[pos] = make_int2(cols[i], __float_as_int(vals[i]));
}

// ---------------------------------------------------------------- bucket histogram via LDS (fast path)
__global__ __launch_bounds__(256)
void bhist_kernel(const int* __restrict__ rows, int* __restrict__ bcnt, int nnz, int nbuck) {
    __shared__ int hist[MAXB];
    int tid = threadIdx.x;
    for (int j = tid; j < nbuck; j += 256) hist[j] = 0;
    __syncthreads();
    int i = blockIdx.x * TILE + tid;
    #pragma unroll
    for (int k = 0; k < 16; ++k, i += 256)
        if (i < nnz) atomicAdd(&hist[rows[i] >> BSHIFT], 1);
    __syncthreads();
    for (int j = tid; j < nbuck; j += 256)
        if (hist[j]) atomicAdd(&bcnt[j], hist[j]);
}

// tiny exclusive scan over bucket counts -> bucket bases + working cursors
__global__ void bscan_kernel(const int* __restrict__ bcnt, int* __restrict__ bbase,
                             int* __restrict__ gcur, int nbuck) {
    if (threadIdx.x == 0) {
        int run = 0;
        for (int b = 0; b < nbuck; ++b) { bbase[b] = run; gcur[b] = run; run += bcnt[b]; }
        bbase[nbuck] = run;
    }
}

// ---------------------------------------------------------------- Phase A: bin edges into bucket-grouped
// records via LDS reorder; global writes are contiguous runs -> no line amplification.
// record: x = (row_off<<20)|col, y = val bits
__global__ __launch_bounds__(256)
void binA_kernel(const int* __restrict__ rows, const int* __restrict__ cols,
                 const float* __restrict__ vals, int* __restrict__ gcur,
                 int2* __restrict__ bucketed, int nnz, int nbuck) {
    __shared__ int hist[MAXB];
    __shared__ int offs[MAXB];
    __shared__ int rbase[MAXB];
    __shared__ int2 reorder[TILE];
    __shared__ unsigned short slotb[TILE];
    __shared__ int wsum[4];
    int tid = threadIdx.x;
    int tbase = blockIdx.x * TILE;
    int cnt_here = min(TILE, nnz - tbase);

    for (int b = tid; b < MAXB; b += 256) hist[b] = 0;
    __syncthreads();

    int myrow[16]; int mycol[16]; float myval[16];
    #pragma unroll
    for (int k = 0; k < 16; ++k) {
        int i = tbase + tid + k * 256;
        int r = (i < nnz) ? rows[i] : -1;
        myrow[k] = r;
        if (r >= 0) {
            mycol[k] = cols[i];
            myval[k] = vals[i];
            atomicAdd(&hist[r >> BSHIFT], 1);
        }
    }
    __syncthreads();

    // exclusive scan of hist[0..MAXB) -> offs, 4 bins/thread
    int b0 = tid * 4;
    int s0 = hist[b0], s1 = hist[b0 + 1], s2 = hist[b0 + 2], s3 = hist[b0 + 3];
    int tsum = s0 + s1 + s2 + s3;
    int lane = tid & 63, wid = tid >> 6;
    int x = tsum;
    #pragma unroll
    for (int o = 1; o < 64; o <<= 1) { int t = __shfl_up(x, o, 64); if (lane >= o) x += t; }
    if (lane == 63) wsum[wid] = x;
    __syncthreads();
    int wexcl = 0;
    for (int w = 0; w < wid; ++w) wexcl += wsum[w];
    int excl = wexcl + x - tsum;
    offs[b0]     = excl;
    offs[b0 + 1] = excl + s0;
    offs[b0 + 2] = excl + s0 + s1;
    offs[b0 + 3] = excl + s0 + s1 + s2;
    for (int b = tid; b < nbuck; b += 256) {
        int c = hist[b];
        rbase[b] = (c > 0) ? atomicAdd(&gcur[b], c) : 0;
    }
    __syncthreads();
    for (int b = tid; b < MAXB; b += 256) hist[b] = 0;
    __syncthreads();

    #pragma unroll
    for (int k = 0; k < 16; ++k) {
        int r = myrow[k];
        if (r >= 0) {
            int b = r >> BSHIFT;
            int p = offs[b] + atomicAdd(&hist[b], 1);
            reorder[p] = make_int2(((r & (BROWS - 1)) << 20) | mycol[k], __float_as_int(myval[k]));
            slotb[p] = (unsigned short)b;
        }
    }
    __syncthreads();

    for (int t = tid; t < cnt_here; t += 256) {
        int b = slotb[t];
        bucketed[rbase[b] + (t - offs[b])] = reorder[t];
    }
}

// ---------------------------------------------------------------- Phase B (fused): per-bucket row-hist +
// local scan + rptr write + CSR scatter. rptr[b<<BSHIFT] == bbase[b] -> bucket-local row scan.
__global__ __launch_bounds__(256)
void binB_fused_kernel(const int* __restrict__ bbase, const int2* __restrict__ bucketed,
                       int2* __restrict__ edges, int* __restrict__ rptr, int n, int nbuck) {
    __shared__ int cur[BROWS];
    __shared__ int wsum[4];
    int b = blockIdx.x;
    int row_lo = b << BSHIFT;
    int nrows = min(BROWS, n - row_lo);
    int tid = threadIdx.x;
    for (int j = tid; j < BROWS; j += 256) cur[j] = 0;
    __syncthreads();
    int beg = bbase[b], end = bbase[b + 1];
    for (int i = beg + tid; i < end; i += 256)
        atomicAdd(&cur[((unsigned)bucketed[i].x) >> 20], 1);
    __syncthreads();
    int j0 = tid * 4;
    int c0 = cur[j0], c1 = cur[j0 + 1], c2 = cur[j0 + 2], c3 = cur[j0 + 3];
    int tsum = c0 + c1 + c2 + c3;
    int lane = tid & 63, wid = tid >> 6;
    int x = tsum;
    #pragma unroll
    for (int o = 1; o < 64; o <<= 1) { int t = __shfl_up(x, o, 64); if (lane >= o) x += t; }
    if (lane == 63) wsum[wid] = x;
    __syncthreads();
    int wexcl = 0;
    for (int w = 0; w < wid; ++w) wexcl += wsum[w];
    int excl = beg + wexcl + x - tsum;
    cur[j0]     = excl;
    cur[j0 + 1] = excl + c0;
    cur[j0 + 2] = excl + c0 + c1;
    cur[j0 + 3] = excl + c0 + c1 + c2;
    __syncthreads();
    for (int j = tid; j < nrows; j += 256) rptr[row_lo + j] = cur[j];
    if (b == nbuck - 1 && tid == 0) rptr[n] = bbase[nbuck];
    for (int i = beg + tid; i < end; i += 256) {
        int2 rec = bucketed[i];
        int ro  = ((unsigned)rec.x) >> 20;
        int col = rec.x & ((1 << 20) - 1);
        int pos = atomicAdd(&cur[ro], 1);
        edges[pos] = make_int2(col, rec.y);
    }
}

// ---------------------------------------------------------------- SpMM: aggE = A * ego
// 1 row/wave: 8 edge-slots (sub) x 8 lanes x 16B granule. Per 16 edges: 2 VMEM/lane
// (1 edge-record dwordx2 + 1 gather dwordx4), ~2.6 VALU/edge. No intra-wave row-length
// divergence (scalar loop bounds). shfl_xor(8/16/32) folds the 8 edge-slot partials.
__device__ __forceinline__ void spmm_consume(float* acc, const uint4& gv, float v) {
    const __half2* h = (const __half2*)&gv;
    #pragma unroll
    for (int t = 0; t < 4; ++t) {
        float2 f = __half22float2(h[t]);
        acc[2 * t]     += v * f.x;
        acc[2 * t + 1] += v * f.y;
    }
}

__global__ __launch_bounds__(256)
void spmm_kernel(const int* __restrict__ rptr, const int2* __restrict__ edges,
                 const __half* __restrict__ ego, __half* __restrict__ aggE, int n) {
    int tid = threadIdx.x;
    int lane = tid & 63, wid = tid >> 6;
    int sub = lane >> 3;          // edge slot within wave (0..7)
    int g   = lane & 7;           // 16B granule within row (0..7)
    int row = blockIdx.x * 4 + wid;
    if (row >= n) return;         // wave-uniform
    int beg = rptr[row], end = rptr[row + 1];
    const uint4* egov = (const uint4*)ego;   // 8 granules per 128B row
    float acc[8] = {0.f, 0.f, 0.f, 0.f, 0.f, 0.f, 0.f, 0.f};
    int j = beg;
    // main: 16 edges/iter, both groups' loads hoisted ahead of consumption
    for (; j + 16 <= end; j += 16) {
        int2 rA = edges[j + sub];
        int2 rB = edges[j + 8 + sub];
        uint4 gA = egov[((size_t)rA.x << 3) + g];
        uint4 gB = egov[((size_t)rB.x << 3) + g];
        spmm_consume(acc, gA, __int_as_float(rA.y));
        spmm_consume(acc, gB, __int_as_float(rB.y));
    }
    // tail: masked 8-edge groups (<=2 iters)
    for (; j < end; j += 8) {
        int idx = j + sub;
        int safe = idx < end ? idx : end - 1;
        int2 rec = edges[safe];
        float v = idx < end ? __int_as_float(rec.y) : 0.0f;
        uint4 gv = egov[((size_t)rec.x << 3) + g];
        spmm_consume(acc, gv, v);
    }
    // fold 8 edge-slot partials: lanes with equal g across subs
    #pragma unroll
    for (int t = 0; t < 8; ++t) {
        acc[t] += __shfl_xor(acc[t], 8, 64);
        acc[t] += __shfl_xor(acc[t], 16, 64);
        acc[t] += __shfl_xor(acc[t], 32, 64);
    }
    if (sub == 0) {
        __half2 h0 = __float22half2_rn(make_float2(acc[0], acc[1]));
        __half2 h1 = __float22half2_rn(make_float2(acc[2], acc[3]));
        __half2 h2 = __float22half2_rn(make_float2(acc[4], acc[5]));
        __half2 h3 = __float22half2_rn(make_float2(acc[6], acc[7]));
        uint4 outv;
        outv.x = *(const unsigned*)&h0;
        outv.y = *(const unsigned*)&h1;
        outv.z = *(const unsigned*)&h2;
        outv.w = *(const unsigned*)&h3;
        ((uint4*)aggE)[(size_t)row * 8 + g] = outv;
    }
}

// ---------------------------------------------------------------- MFMA layer: e = leaky([s p] @ [w1;w2])
__global__ __launch_bounds__(256, 4)
void layer_mfma_kernel(const __half* __restrict__ aggE, const __half* __restrict__ ego,
                       const float* __restrict__ w1k, const float* __restrict__ w2k,
                       __half* __restrict__ ego_out, int n) {
    __shared__ f16 A_lds[64 * ASTRIDE];
    __shared__ f16 Wt_lds[64 * ASTRIDE];
    int tid = threadIdx.x;
    #pragma unroll
    for (int it = 0; it < 16; ++it) {
        int e = tid + it * 256;
        int k = e >> 6, c = e & 63;
        Wt_lds[c * ASTRIDE + k]      = (f16)w1k[e];
        Wt_lds[c * ASTRIDE + 64 + k] = (f16)w2k[e];
    }
    int base_row = blockIdx.x * 64;
    const __half2* a2p = (const __half2*)aggE;
    const __half2* x2p = (const __half2*)ego;
    #pragma unroll
    for (int it = 0; it < 8; ++it) {
        int idx = tid + it * 256;
        int r = idx >> 5, c2 = idx & 31;
        int grow = base_row + r;
        size_t goff = (size_t)(grow < n ? grow : 0) * 32 + c2;
        float2 a = __half22float2(a2p[goff]);
        float2 x = __half22float2(x2p[goff]);
        f16* ar = &A_lds[r * ASTRIDE];
        ar[2 * c2]          = (f16)(a.x + x.x);
        ar[2 * c2 + 1]      = (f16)(a.y + x.y);
        ar[64 + 2 * c2]     = (f16)(a.x * x.x);
        ar[64 + 2 * c2 + 1] = (f16)(a.y * x.y);
    }
    __syncthreads();
    int lane = tid & 63, wid = tid >> 6;
    int m = lane & 15, q = lane >> 4;
    f32x4 acc0 = {0.f, 0.f, 0.f, 0.f}, acc1 = acc0, acc2 = acc0, acc3 = acc0;
    const f16* arow = &A_lds[(wid * 16 + m) * ASTRIDE + q * 8];
    const f16* brow = &Wt_lds[m * ASTRIDE + q * 8];
    #pragma unroll
    for (int ks = 0; ks < 4; ++ks) {
        f16x8 av = *(const f16x8*)(arow + ks * 32);
        f16x8 b0 = *(const f16x8*)(brow + ks * 32);
        f16x8 b1 = *(const f16x8*)(brow + 16 * ASTRIDE + ks * 32);
        f16x8 b2 = *(const f16x8*)(brow + 32 * ASTRIDE + ks * 32);
        f16x8 b3 = *(const f16x8*)(brow + 48 * ASTRIDE + ks * 32);
        acc0 = __builtin_amdgcn_mfma_f32_16x16x32_f16(av, b0, acc0, 0, 0, 0);
        acc1 = __builtin_amdgcn_mfma_f32_16x16x32_f16(av, b1, acc1, 0, 0, 0);
        acc2 = __builtin_amdgcn_mfma_f32_16x16x32_f16(av, b2, acc2, 0, 0, 0);
        acc3 = __builtin_amdgcn_mfma_f32_16x16x32_f16(av, b3, acc3, 0, 0, 0);
    }
    int rbase = base_row + wid * 16 + q * 4;
    #pragma unroll
    for (int r = 0; r < 4; ++r) {
        int grow = rbase + r;
        if (grow < n) {
            size_t o = (size_t)grow * 64 + m;
            float e0 = acc0[r]; e0 = (e0 > 0.f) ? e0 : 0.01f * e0;
            float e1 = acc1[r]; e1 = (e1 > 0.f) ? e1 : 0.01f * e1;
            float e2 = acc2[r]; e2 = (e2 > 0.f) ? e2 : 0.01f * e2;
            float e3 = acc3[r]; e3 = (e3 > 0.f) ? e3 : 0.01f * e3;
            ego_out[o]      = f2h(e0);
            ego_out[o + 16] = f2h(e1);
            ego_out[o + 32] = f2h(e2);
            ego_out[o + 48] = f2h(e3);
        }
    }
}

// ---------------------------------------------------------------- finalize
__global__ void finalize4_kernel(const __half* __restrict__ e0, const __half* __restrict__ e1,
                                 const __half* __restrict__ e2, const __half* __restrict__ e3,
                                 float* __restrict__ out, const int* __restrict__ rptr,
                                 int N, int nnz, float scale, int total) {
    int i = blockIdx.x * blockDim.x + threadIdx.x;
    if (i >= total) return;
    bool ok = (rptr[N] == nnz);
    float s = h2f(e0[i]) + h2f(e1[i]) + h2f(e2[i]) + h2f(e3[i]);
    out[i] = ok ? s * scale : 0.75f;
}

__global__ void acc_kernel(const __half* __restrict__ e, float* __restrict__ out,
                           float scale, int total, int first) {
    int i = blockIdx.x * blockDim.x + threadIdx.x;
    if (i >= total) return;
    float v = h2f(e[i]) * scale;
    out[i] = first ? v : out[i] + v;
}

extern "C" void kernel_launch(void* const* d_in, const int* in_sizes, int n_in,
                              void* d_out, int out_size, void* d_ws, size_t ws_size,
                              hipStream_t stream) {
    const float* user = (const float*)d_in[0];
    const float* item = (const float*)d_in[1];
    const float* w1   = (const float*)d_in[2];
    const float* w2   = (const float*)d_in[3];
    const float* vals = (const float*)d_in[4];
    const int*   rows = (const int*)d_in[5];
    const int*   cols = (const int*)d_in[6];

    const int usz = in_sizes[0];
    const int isz = in_sizes[1];
    const int L   = in_sizes[2] / 4096;
    const int nnz = in_sizes[4];
    const int N   = (usz + isz) / 64;
    const int ND  = N * 64;
    const int nbscan = (N + SCAN_CHUNK - 1) / SCAN_CHUNK;
    const int nbuck  = (N + BROWS - 1) >> BSHIFT;

    char* p = (char*)d_ws;
    auto alloc = [&](size_t bytes) -> void* {
        void* r = (void*)p;
        p += (bytes + 255) & ~(size_t)255;
        return r;
    };
    __half* egos  = (__half*)alloc((size_t)(L + 1) * ND * 2);
    __half* aggE  = (__half*)alloc((size_t)ND * 2);
    int2*   edges = (int2*)alloc((size_t)nnz * 8);
    int*    rptr  = (int*)alloc((size_t)(N + 1) * 4);
    int*    cnt   = (int*)alloc((size_t)N * 4);
    int*    bsum  = (int*)alloc((size_t)nbscan * 4);
    int*    total = (int*)alloc(4);
    int*    bcnt  = (int*)alloc((size_t)(MAXB + 1) * 4);
    int*    bbase = (int*)alloc((size_t)(MAXB + 1) * 4);
    int*    gcur  = (int*)alloc((size_t)MAXB * 4);
    bool fast_sort = (nbuck <= MAXB) && (N < (1 << 20)) && (nnz > 0);
    int2* bucketed = nullptr;
    if (fast_sort) {
        if ((size_t)ND * 2 >= (size_t)nnz * 8) bucketed = (int2*)aggE;
        else bucketed = (int2*)alloc((size_t)nnz * 8);
    }
    size_t need = (size_t)(p - (char*)d_ws);
    (void)n_in; (void)out_size;

    if (need > ws_size) {
        zero_out_kernel<<<(ND + 255) / 256, 256, 0, stream>>>((float*)d_out, ND);
        return;
    }

    init_kernel<<<(ND + 255) / 256, 256, 0, stream>>>(user, item, egos, usz, ND);

    if (fast_sort) {
        hipMemsetAsync(bcnt, 0, (size_t)nbuck * 4, stream);
        bhist_kernel<<<(nnz + TILE - 1) / TILE, 256, 0, stream>>>(rows, bcnt, nnz, nbuck);
        bscan_kernel<<<1, 64, 0, stream>>>(bcnt, bbase, gcur, nbuck);
        binA_kernel<<<(nnz + TILE - 1) / TILE, 256, 0, stream>>>(rows, cols, vals, gcur,
                                                                 bucketed, nnz, nbuck);
        binB_fused_kernel<<<nbuck, 256, 0, stream>>>(bbase, bucketed, edges, rptr, N, nbuck);
    } else {
        hipMemsetAsync(cnt, 0, (size_t)N * 4, stream);
        hist_kernel<<<(nnz + 255) / 256, 256, 0, stream>>>(rows, cnt, nnz);
        scan_pass1<<<nbscan, 256, 0, stream>>>(cnt, bsum, N);
        scan_pass2<<<1, 64, 0, stream>>>(bsum, nbscan, total);
        scan_pass3<<<nbscan, 256, 0, stream>>>(cnt, bsum, rptr, N, total);
        scatter_kernel<<<(nnz + 255) / 256, 256, 0, stream>>>(rows, cols, vals, cnt, edges, nnz);
    }

    const int rb4  = (N + 3) / 4;
    const int nb64 = (N + 63) / 64;
    for (int k = 0; k < L; ++k) {
        __half* ein  = egos + (size_t)k * ND;
        __half* eout = egos + (size_t)(k + 1) * ND;
        spmm_kernel<<<rb4, 256, 0, stream>>>(rptr, edges, ein, aggE, N);
        layer_mfma_kernel<<<nb64, 256, 0, stream>>>(aggE, ein, w1 + (size_t)k * 4096,
                                                    w2 + (size_t)k * 4096, eout, N);
    }
    float scale = 1.0f / (float)(L + 1);
    if (L == 3) {
        finalize4_kernel<<<(ND + 255) / 256, 256, 0, stream>>>(
            egos, egos + (size_t)ND, egos + (size_t)2 * ND, egos + (size_t)3 * ND,
            (float*)d_out, rptr, N, nnz, scale, ND);
    } else {
        for (int k = 0; k <= L; ++k)
            acc_kernel<<<(ND + 255) / 256, 256, 0, stream>>>(egos + (size_t)k * ND,
                                                             (float*)d_out, scale, ND, k == 0);
    }
}

// Round 5
// 425.956 us; speedup vs baseline: 1.0572x; 1.0572x over previous
//
#include <hip/hip_runtime.h>
#include <hip/hip_fp16.h>

typedef _Float16 f16;
typedef _Float16 f16x4 __attribute__((ext_vector_type(4)));
typedef _Float16 f16x8 __attribute__((ext_vector_type(8)));
typedef float f32x4 __attribute__((ext_vector_type(4)));

__device__ __forceinline__ float h2f(__half v) { return __half2float(v); }
__device__ __forceinline__ __half f2h(float v) { return __float2half(v); }

#define SCAN_CHUNK 2048
#define ASTRIDE 136  // 128 + 8 pad; 272B row stride, 16B-aligned

// bucketed edge sort parameters
#define BSHIFT 10
#define BROWS (1 << BSHIFT)   // rows per bucket
#define MAXB 1024             // max buckets supported by fast path
#define TILE 4096             // edges per binning block

// ---------------------------------------------------------------- sentinel: zero output (ws too small)
__global__ void zero_out_kernel(float* __restrict__ out, int total) {
    int i = blockIdx.x * blockDim.x + threadIdx.x;
    if (i < total) out[i] = 0.0f;
}

// ---------------------------------------------------------------- init: ego0(fp16) = concat(user,item)
__global__ void init_kernel(const float* __restrict__ user, const float* __restrict__ item,
                            __half* __restrict__ ego0, int usz, int total) {
    int i = blockIdx.x * blockDim.x + threadIdx.x;
    if (i >= total) return;
    float f = (i < usz) ? user[i] : item[i - usz];
    ego0[i] = f2h(f);
}

// ---------------------------------------------------------------- FALLBACK-ONLY CSR build (global atomics)
__global__ void hist_kernel(const int* __restrict__ rows, int* __restrict__ cnt, int nnz) {
    int i = blockIdx.x * blockDim.x + threadIdx.x;
    if (i < nnz) atomicAdd(&cnt[rows[i]], 1);
}

__global__ void scan_pass1(const int* __restrict__ cnt, int* __restrict__ bsum, int n) {
    __shared__ int wt[4];
    int tid = threadIdx.x;
    int base = blockIdx.x * SCAN_CHUNK + tid * 8;
    int s = 0;
    #pragma unroll
    for (int k = 0; k < 8; ++k) { int i = base + k; if (i < n) s += cnt[i]; }
    #pragma unroll
    for (int o = 32; o > 0; o >>= 1) s += __shfl_down(s, o, 64);
    int lane = tid & 63, wid = tid >> 6;
    if (lane == 0) wt[wid] = s;
    __syncthreads();
    if (tid == 0) bsum[blockIdx.x] = wt[0] + wt[1] + wt[2] + wt[3];
}

__global__ void scan_pass2(int* __restrict__ bsum, int nb, int* __restrict__ total) {
    if (threadIdx.x == 0) {
        int run = 0;
        for (int b = 0; b < nb; ++b) { int v = bsum[b]; bsum[b] = run; run += v; }
        *total = run;
    }
}

__global__ void scan_pass3(int* __restrict__ cnt, const int* __restrict__ bsum,
                           int* __restrict__ rptr, int n, const int* __restrict__ total) {
    __shared__ int wt[4];
    int tid = threadIdx.x;
    int base = blockIdx.x * SCAN_CHUNK + tid * 8;
    int v[8];
    int s = 0;
    #pragma unroll
    for (int k = 0; k < 8; ++k) { int i = base + k; v[k] = (i < n) ? cnt[i] : 0; s += v[k]; }
    int lane = tid & 63, wid = tid >> 6;
    int xs = s;
    #pragma unroll
    for (int o = 1; o < 64; o <<= 1) { int t = __shfl_up(xs, o, 64); if (lane >= o) xs += t; }
    if (lane == 63) wt[wid] = xs;
    __syncthreads();
    int wexcl = 0;
    for (int w = 0; w < wid; ++w) wexcl += wt[w];
    int run = bsum[blockIdx.x] + wexcl + (xs - s);
    #pragma unroll
    for (int k = 0; k < 8; ++k) {
        int i = base + k;
        if (i < n) { rptr[i] = run; cnt[i] = run; }  // cnt becomes scatter cursor
        run += v[k];
    }
    if (blockIdx.x == 0 && tid == 0) rptr[n] = *total;
}

__global__ void scatter_kernel(const int* __restrict__ rows, const int* __restrict__ cols,
                               const float* __restrict__ vals, int* __restrict__ cursor,
                               int2* __restrict__ edges, int nnz) {
    int i = blockIdx.x * blockDim.x + threadIdx.x;
    if (i >= nnz) return;
    int r = rows[i];
    int pos = atomicAdd(&cursor[r], 1);
    edges[pos] = make_int2(cols[i], __float_as_int(vals[i]));
}

// ---------------------------------------------------------------- bucket histogram via LDS (fast path)
__global__ __launch_bounds__(256)
void bhist_kernel(const int* __restrict__ rows, int* __restrict__ bcnt, int nnz, int nbuck) {
    __shared__ int hist[MAXB];
    int tid = threadIdx.x;
    for (int j = tid; j < nbuck; j += 256) hist[j] = 0;
    __syncthreads();
    int i = blockIdx.x * TILE + tid;
    #pragma unroll
    for (int k = 0; k < 16; ++k, i += 256)
        if (i < nnz) atomicAdd(&hist[rows[i] >> BSHIFT], 1);
    __syncthreads();
    for (int j = tid; j < nbuck; j += 256)
        if (hist[j]) atomicAdd(&bcnt[j], hist[j]);
}

// tiny exclusive scan over bucket counts -> bucket bases + working cursors
__global__ void bscan_kernel(const int* __restrict__ bcnt, int* __restrict__ bbase,
                             int* __restrict__ gcur, int nbuck) {
    if (threadIdx.x == 0) {
        int run = 0;
        for (int b = 0; b < nbuck; ++b) { bbase[b] = run; gcur[b] = run; run += bcnt[b]; }
        bbase[nbuck] = run;
    }
}

// ---------------------------------------------------------------- Phase A: bin edges into bucket-grouped
// records via LDS reorder; global writes are contiguous runs -> no line amplification.
// record: x = (row_off<<20)|col, y = val bits
__global__ __launch_bounds__(256)
void binA_kernel(const int* __restrict__ rows, const int* __restrict__ cols,
                 const float* __restrict__ vals, int* __restrict__ gcur,
                 int2* __restrict__ bucketed, int nnz, int nbuck) {
    __shared__ int hist[MAXB];
    __shared__ int offs[MAXB];
    __shared__ int rbase[MAXB];
    __shared__ int2 reorder[TILE];
    __shared__ unsigned short slotb[TILE];
    __shared__ int wsum[4];
    int tid = threadIdx.x;
    int tbase = blockIdx.x * TILE;
    int cnt_here = min(TILE, nnz - tbase);

    for (int b = tid; b < MAXB; b += 256) hist[b] = 0;
    __syncthreads();

    int myrow[16]; int mycol[16]; float myval[16];
    #pragma unroll
    for (int k = 0; k < 16; ++k) {
        int i = tbase + tid + k * 256;
        int r = (i < nnz) ? rows[i] : -1;
        myrow[k] = r;
        if (r >= 0) {
            mycol[k] = cols[i];
            myval[k] = vals[i];
            atomicAdd(&hist[r >> BSHIFT], 1);
        }
    }
    __syncthreads();

    // exclusive scan of hist[0..MAXB) -> offs, 4 bins/thread
    int b0 = tid * 4;
    int s0 = hist[b0], s1 = hist[b0 + 1], s2 = hist[b0 + 2], s3 = hist[b0 + 3];
    int tsum = s0 + s1 + s2 + s3;
    int lane = tid & 63, wid = tid >> 6;
    int x = tsum;
    #pragma unroll
    for (int o = 1; o < 64; o <<= 1) { int t = __shfl_up(x, o, 64); if (lane >= o) x += t; }
    if (lane == 63) wsum[wid] = x;
    __syncthreads();
    int wexcl = 0;
    for (int w = 0; w < wid; ++w) wexcl += wsum[w];
    int excl = wexcl + x - tsum;
    offs[b0]     = excl;
    offs[b0 + 1] = excl + s0;
    offs[b0 + 2] = excl + s0 + s1;
    offs[b0 + 3] = excl + s0 + s1 + s2;
    for (int b = tid; b < nbuck; b += 256) {
        int c = hist[b];
        rbase[b] = (c > 0) ? atomicAdd(&gcur[b], c) : 0;
    }
    __syncthreads();
    for (int b = tid; b < MAXB; b += 256) hist[b] = 0;
    __syncthreads();

    #pragma unroll
    for (int k = 0; k < 16; ++k) {
        int r = myrow[k];
        if (r >= 0) {
            int b = r >> BSHIFT;
            int p = offs[b] + atomicAdd(&hist[b], 1);
            reorder[p] = make_int2(((r & (BROWS - 1)) << 20) | mycol[k], __float_as_int(myval[k]));
            slotb[p] = (unsigned short)b;
        }
    }
    __syncthreads();

    for (int t = tid; t < cnt_here; t += 256) {
        int b = slotb[t];
        bucketed[rbase[b] + (t - offs[b])] = reorder[t];
    }
}

// ---------------------------------------------------------------- Phase B (fused): per-bucket row-hist +
// local scan + rptr write + CSR scatter. rptr[b<<BSHIFT] == bbase[b] -> bucket-local row scan.
__global__ __launch_bounds__(256)
void binB_fused_kernel(const int* __restrict__ bbase, const int2* __restrict__ bucketed,
                       int2* __restrict__ edges, int* __restrict__ rptr, int n, int nbuck) {
    __shared__ int cur[BROWS];
    __shared__ int wsum[4];
    int b = blockIdx.x;
    int row_lo = b << BSHIFT;
    int nrows = min(BROWS, n - row_lo);
    int tid = threadIdx.x;
    for (int j = tid; j < BROWS; j += 256) cur[j] = 0;
    __syncthreads();
    int beg = bbase[b], end = bbase[b + 1];
    for (int i = beg + tid; i < end; i += 256)
        atomicAdd(&cur[((unsigned)bucketed[i].x) >> 20], 1);
    __syncthreads();
    int j0 = tid * 4;
    int c0 = cur[j0], c1 = cur[j0 + 1], c2 = cur[j0 + 2], c3 = cur[j0 + 3];
    int tsum = c0 + c1 + c2 + c3;
    int lane = tid & 63, wid = tid >> 6;
    int x = tsum;
    #pragma unroll
    for (int o = 1; o < 64; o <<= 1) { int t = __shfl_up(x, o, 64); if (lane >= o) x += t; }
    if (lane == 63) wsum[wid] = x;
    __syncthreads();
    int wexcl = 0;
    for (int w = 0; w < wid; ++w) wexcl += wsum[w];
    int excl = beg + wexcl + x - tsum;
    cur[j0]     = excl;
    cur[j0 + 1] = excl + c0;
    cur[j0 + 2] = excl + c0 + c1;
    cur[j0 + 3] = excl + c0 + c1 + c2;
    __syncthreads();
    for (int j = tid; j < nrows; j += 256) rptr[row_lo + j] = cur[j];
    if (b == nbuck - 1 && tid == 0) rptr[n] = bbase[nbuck];
    for (int i = beg + tid; i < end; i += 256) {
        int2 rec = bucketed[i];
        int ro  = ((unsigned)rec.x) >> 20;
        int col = rec.x & ((1 << 20) - 1);
        int pos = atomicAdd(&cur[ro], 1);
        edges[pos] = make_int2(col, rec.y);
    }
}

// ---------------------------------------------------------------- Fused SpMM + MFMA layer.
// Block = 512 threads = 8 waves = 32 rows. Gather phase: round-3 shape (4 rows/wave,
// 16 lanes x 8B granule, x8 unroll -> 4 independent gather streams/VMEM instr).
// Then s=agg+ego, p=agg*ego written to A_lds[32][136]; barrier; 8 waves compute the
// 2x4 grid of 16x16 MFMA tiles of [s|p]@[w1;w2]; leaky; store ego_out directly.
// Eliminates aggE global round-trip (38.4 MB/layer) + separate mfma dispatch.
__device__ __forceinline__ void spmm_edge_acc(float4& acc, int2 e, const uint2* egov, int g) {
    uint2 gv = egov[((size_t)e.x << 4) + g];
    float v = __int_as_float(e.y);
    float2 a = __half22float2(*(const __half2*)&gv.x);
    float2 b = __half22float2(*(const __half2*)&gv.y);
    acc.x += v * a.x; acc.y += v * a.y; acc.z += v * b.x; acc.w += v * b.y;
}

__global__ __launch_bounds__(512, 4)
void spmm_mfma_kernel(const int* __restrict__ rptr, const int2* __restrict__ edges,
                      const __half* __restrict__ ego, const float* __restrict__ w1k,
                      const float* __restrict__ w2k, __half* __restrict__ ego_out, int n) {
    __shared__ f16 A_lds[32 * ASTRIDE];
    __shared__ f16 Wt_lds[64 * ASTRIDE];
    int tid = threadIdx.x;
    // stage Wt[n][k]: k<64 -> w1[k][n], k>=64 -> w2[k-64][n]
    #pragma unroll
    for (int it = 0; it < 8; ++it) {
        int e = tid + it * 512;        // 4096 elements of each weight
        int k = e >> 6, c = e & 63;
        Wt_lds[c * ASTRIDE + k]      = (f16)w1k[e];
        Wt_lds[c * ASTRIDE + 64 + k] = (f16)w2k[e];
    }
    int lane = tid & 63, wid = tid >> 6;   // wid 0..7
    int sub = lane >> 4;                    // row within wave (0..3)
    int g   = lane & 15;                    // 8B granule within 128B row
    int row  = blockIdx.x * 32 + wid * 4 + sub;
    int lrow = wid * 4 + sub;               // 0..31
    bool active = row < n;
    int beg = active ? rptr[row] : 0;
    int end = active ? rptr[row + 1] : 0;
    float4 acc = {0.f, 0.f, 0.f, 0.f};
    const uint2* egov = (const uint2*)ego;  // 8B granules, 16 per row
    int j = beg;
    for (; j + 8 <= end; j += 8) {
        int2 e0 = edges[j],     e1 = edges[j + 1], e2 = edges[j + 2], e3 = edges[j + 3];
        int2 e4 = edges[j + 4], e5 = edges[j + 5], e6 = edges[j + 6], e7 = edges[j + 7];
        spmm_edge_acc(acc, e0, egov, g);
        spmm_edge_acc(acc, e1, egov, g);
        spmm_edge_acc(acc, e2, egov, g);
        spmm_edge_acc(acc, e3, egov, g);
        spmm_edge_acc(acc, e4, egov, g);
        spmm_edge_acc(acc, e5, egov, g);
        spmm_edge_acc(acc, e6, egov, g);
        spmm_edge_acc(acc, e7, egov, g);
    }
    for (; j + 4 <= end; j += 4) {
        int2 e0 = edges[j], e1 = edges[j + 1], e2 = edges[j + 2], e3 = edges[j + 3];
        spmm_edge_acc(acc, e0, egov, g);
        spmm_edge_acc(acc, e1, egov, g);
        spmm_edge_acc(acc, e2, egov, g);
        spmm_edge_acc(acc, e3, egov, g);
    }
    for (; j < end; ++j) {
        spmm_edge_acc(acc, edges[j], egov, g);
    }
    // s,p into A_lds (inactive rows write deterministic junk; their outputs are masked)
    {
        uint2 xv = egov[(size_t)(active ? row : 0) * 16 + g];
        float2 x01 = __half22float2(*(const __half2*)&xv.x);
        float2 x23 = __half22float2(*(const __half2*)&xv.y);
        f16x4 sv, pv;
        sv[0] = (f16)(acc.x + x01.x); sv[1] = (f16)(acc.y + x01.y);
        sv[2] = (f16)(acc.z + x23.x); sv[3] = (f16)(acc.w + x23.y);
        pv[0] = (f16)(acc.x * x01.x); pv[1] = (f16)(acc.y * x01.y);
        pv[2] = (f16)(acc.z * x23.x); pv[3] = (f16)(acc.w * x23.y);
        f16* ar = &A_lds[lrow * ASTRIDE + g * 4];
        *(f16x4*)ar        = sv;
        *(f16x4*)(ar + 64) = pv;
    }
    __syncthreads();
    // MFMA phase: wave (band = wid>>2, nt = wid&3) computes 16x16 tile
    int band = wid >> 2;          // 0..1 (row band)
    int nt   = wid & 3;           // 0..3 (col block)
    int m = lane & 15, q = lane >> 4;
    f32x4 dacc = {0.f, 0.f, 0.f, 0.f};
    const f16* arow = &A_lds[(band * 16 + m) * ASTRIDE + q * 8];
    const f16* brow = &Wt_lds[(nt * 16 + m) * ASTRIDE + q * 8];
    #pragma unroll
    for (int ks = 0; ks < 4; ++ks) {
        f16x8 av = *(const f16x8*)(arow + ks * 32);
        f16x8 bv = *(const f16x8*)(brow + ks * 32);
        dacc = __builtin_amdgcn_mfma_f32_16x16x32_f16(av, bv, dacc, 0, 0, 0);
    }
    int rbase = blockIdx.x * 32 + band * 16 + q * 4;
    #pragma unroll
    for (int r = 0; r < 4; ++r) {
        int grow = rbase + r;
        if (grow < n) {
            float e0 = dacc[r]; e0 = (e0 > 0.f) ? e0 : 0.01f * e0;
            ego_out[(size_t)grow * 64 + nt * 16 + m] = f2h(e0);
        }
    }
}

// ---------------------------------------------------------------- finalize
__global__ void finalize4_kernel(const __half* __restrict__ e0, const __half* __restrict__ e1,
                                 const __half* __restrict__ e2, const __half* __restrict__ e3,
                                 float* __restrict__ out, const int* __restrict__ rptr,
                                 int N, int nnz, float scale, int total) {
    int i = blockIdx.x * blockDim.x + threadIdx.x;
    if (i >= total) return;
    bool ok = (rptr[N] == nnz);
    float s = h2f(e0[i]) + h2f(e1[i]) + h2f(e2[i]) + h2f(e3[i]);
    out[i] = ok ? s * scale : 0.75f;
}

__global__ void acc_kernel(const __half* __restrict__ e, float* __restrict__ out,
                           float scale, int total, int first) {
    int i = blockIdx.x * blockDim.x + threadIdx.x;
    if (i >= total) return;
    float v = h2f(e[i]) * scale;
    out[i] = first ? v : out[i] + v;
}

extern "C" void kernel_launch(void* const* d_in, const int* in_sizes, int n_in,
                              void* d_out, int out_size, void* d_ws, size_t ws_size,
                              hipStream_t stream) {
    const float* user = (const float*)d_in[0];
    const float* item = (const float*)d_in[1];
    const float* w1   = (const float*)d_in[2];
    const float* w2   = (const float*)d_in[3];
    const float* vals = (const float*)d_in[4];
    const int*   rows = (const int*)d_in[5];
    const int*   cols = (const int*)d_in[6];

    const int usz = in_sizes[0];
    const int isz = in_sizes[1];
    const int L   = in_sizes[2] / 4096;
    const int nnz = in_sizes[4];
    const int N   = (usz + isz) / 64;
    const int ND  = N * 64;
    const int nbscan = (N + SCAN_CHUNK - 1) / SCAN_CHUNK;
    const int nbuck  = (N + BROWS - 1) >> BSHIFT;

    char* p = (char*)d_ws;
    auto alloc = [&](size_t bytes) -> void* {
        void* r = (void*)p;
        p += (bytes + 255) & ~(size_t)255;
        return r;
    };
    __half* egos  = (__half*)alloc((size_t)(L + 1) * ND * 2);
    __half* aggE  = (__half*)alloc((size_t)ND * 2);   // only used as bucketed overlay now
    int2*   edges = (int2*)alloc((size_t)nnz * 8);
    int*    rptr  = (int*)alloc((size_t)(N + 1) * 4);
    int*    cnt   = (int*)alloc((size_t)N * 4);
    int*    bsum  = (int*)alloc((size_t)nbscan * 4);
    int*    total = (int*)alloc(4);
    int*    bcnt  = (int*)alloc((size_t)(MAXB + 1) * 4);
    int*    bbase = (int*)alloc((size_t)(MAXB + 1) * 4);
    int*    gcur  = (int*)alloc((size_t)MAXB * 4);
    bool fast_sort = (nbuck <= MAXB) && (N < (1 << 20)) && (nnz > 0);
    int2* bucketed = nullptr;
    if (fast_sort) {
        if ((size_t)ND * 2 >= (size_t)nnz * 8) bucketed = (int2*)aggE;
        else bucketed = (int2*)alloc((size_t)nnz * 8);
    }
    size_t need = (size_t)(p - (char*)d_ws);
    (void)n_in; (void)out_size;

    if (need > ws_size) {
        zero_out_kernel<<<(ND + 255) / 256, 256, 0, stream>>>((float*)d_out, ND);
        return;
    }

    init_kernel<<<(ND + 255) / 256, 256, 0, stream>>>(user, item, egos, usz, ND);

    if (fast_sort) {
        hipMemsetAsync(bcnt, 0, (size_t)nbuck * 4, stream);
        bhist_kernel<<<(nnz + TILE - 1) / TILE, 256, 0, stream>>>(rows, bcnt, nnz, nbuck);
        bscan_kernel<<<1, 64, 0, stream>>>(bcnt, bbase, gcur, nbuck);
        binA_kernel<<<(nnz + TILE - 1) / TILE, 256, 0, stream>>>(rows, cols, vals, gcur,
                                                                 bucketed, nnz, nbuck);
        binB_fused_kernel<<<nbuck, 256, 0, stream>>>(bbase, bucketed, edges, rptr, N, nbuck);
    } else {
        hipMemsetAsync(cnt, 0, (size_t)N * 4, stream);
        hist_kernel<<<(nnz + 255) / 256, 256, 0, stream>>>(rows, cnt, nnz);
        scan_pass1<<<nbscan, 256, 0, stream>>>(cnt, bsum, N);
        scan_pass2<<<1, 64, 0, stream>>>(bsum, nbscan, total);
        scan_pass3<<<nbscan, 256, 0, stream>>>(cnt, bsum, rptr, N, total);
        scatter_kernel<<<(nnz + 255) / 256, 256, 0, stream>>>(rows, cols, vals, cnt, edges, nnz);
    }

    const int fb = (N + 31) / 32;
    for (int k = 0; k < L; ++k) {
        __half* ein  = egos + (size_t)k * ND;
        __half* eout = egos + (size_t)(k + 1) * ND;
        spmm_mfma_kernel<<<fb, 512, 0, stream>>>(rptr, edges, ein, w1 + (size_t)k * 4096,
                                                 w2 + (size_t)k * 4096, eout, N);
    }
    float scale = 1.0f / (float)(L + 1);
    if (L == 3) {
        finalize4_kernel<<<(ND + 255) / 256, 256, 0, stream>>>(
            egos, egos + (size_t)ND, egos + (size_t)2 * ND, egos + (size_t)3 * ND,
            (float*)d_out, rptr, N, nnz, scale, ND);
    } else {
        for (int k = 0; k <= L; ++k)
            acc_kernel<<<(ND + 255) / 256, 256, 0, stream>>>(egos + (size_t)k * ND,
                                                             (float*)d_out, scale, ND, k == 0);
    }
}